// Round 5
// baseline (82.081 us; speedup 1.0000x reference)
//
#include <hip/hip_runtime.h>

// 4-qubit statevector QNN. Two samples per thread -> 12 contiguous output
// floats = 3 aligned float4 stores, fully coalesced, no LDS staging.
// Layer-0 RY fused into initial angles; layer-2 RY folded into <Z>.
// HW trig in revolutions. Hardened addressing (size_t offsets, guarded tail).

#define INV_2PI 0.15915494309189535f

template <int MASK>
__device__ __forceinline__ void apply_ry(float st[16], float c, float s) {
#pragma unroll
    for (int i = 0; i < 16; ++i) {
        if (!(i & MASK)) {
            float a0 = st[i];
            float a1 = st[i | MASK];
            st[i]        = fmaf(c, a0, -s * a1);
            st[i | MASK] = fmaf(s, a0,  c * a1);
        }
    }
}

template <int CMASK, int TMASK>
__device__ __forceinline__ void apply_cnot(float st[16]) {
#pragma unroll
    for (int i = 0; i < 16; ++i) {
        if ((i & CMASK) && !(i & TMASK)) {
            float tmp     = st[i];
            st[i]         = st[i | TMASK];
            st[i | TMASK] = tmp;
        }
    }
}

__device__ __forceinline__ void run_sample(
    float x0, float x1, float x2, float x3,
    const float* __restrict__ qw0,
    const float* __restrict__ c1h, const float* __restrict__ s1h,
    const float* __restrict__ c2f, const float* __restrict__ s2f,
    const float* __restrict__ sW,  const float* __restrict__ sb,
    float o[6])
{
    float c0, s0, c1, s1, c2, s2, c3, s3;
    {
        float r0 = (x0 + qw0[0]) * (0.5f * INV_2PI);
        float r1 = (x1 + qw0[1]) * (0.5f * INV_2PI);
        float r2 = (x2 + qw0[2]) * (0.5f * INV_2PI);
        float r3 = (x3 + qw0[3]) * (0.5f * INV_2PI);
        c0 = __builtin_amdgcn_cosf(r0); s0 = __builtin_amdgcn_sinf(r0);
        c1 = __builtin_amdgcn_cosf(r1); s1 = __builtin_amdgcn_sinf(r1);
        c2 = __builtin_amdgcn_cosf(r2); s2 = __builtin_amdgcn_sinf(r2);
        c3 = __builtin_amdgcn_cosf(r3); s3 = __builtin_amdgcn_sinf(r3);
    }

    float a01[4] = { c0 * c1, c0 * s1, s0 * c1, s0 * s1 };  // bits 8,4
    float a23[4] = { c2 * c3, c2 * s3, s2 * c3, s2 * s3 };  // bits 2,1

    float st[16];
#pragma unroll
    for (int hi = 0; hi < 4; ++hi)
#pragma unroll
        for (int lo = 0; lo < 4; ++lo)
            st[hi * 4 + lo] = a01[hi] * a23[lo];

    apply_cnot<8, 4>(st); apply_cnot<4, 2>(st);
    apply_cnot<2, 1>(st); apply_cnot<1, 8>(st);

    apply_ry<8>(st, c1h[0], s1h[0]);
    apply_ry<4>(st, c1h[1], s1h[1]);
    apply_ry<2>(st, c1h[2], s1h[2]);
    apply_ry<1>(st, c1h[3], s1h[3]);

    apply_cnot<8, 4>(st); apply_cnot<4, 2>(st);
    apply_cnot<2, 1>(st); apply_cnot<1, 8>(st);

    float p[16];
#pragma unroll
    for (int i = 0; i < 16; ++i) p[i] = st[i] * st[i];

    float z[4];
#pragma unroll
    for (int w = 0; w < 4; ++w) {
        const int m = 8 >> w;
        float A1 = 0.0f, X = 0.0f;
#pragma unroll
        for (int i = 0; i < 16; ++i) {
            if (!(i & m)) {
                A1 += p[i | m];
                X  = fmaf(st[i], st[i | m], X);
            }
        }
        z[w] = fmaf(c2f[w], fmaf(-2.0f, A1, 1.0f), -2.0f * s2f[w] * X);
    }

    float e[6];
    float sum = 0.0f;
#pragma unroll
    for (int j = 0; j < 6; ++j) {
        float a = sb[j];
        a = fmaf(z[0], sW[j * 4 + 0], a);
        a = fmaf(z[1], sW[j * 4 + 1], a);
        a = fmaf(z[2], sW[j * 4 + 2], a);
        a = fmaf(z[3], sW[j * 4 + 3], a);
        e[j] = __expf(a);
        sum += e[j];
    }
    const float inv = __builtin_amdgcn_rcpf(sum);
#pragma unroll
    for (int j = 0; j < 6; ++j) o[j] = e[j] * inv;
}

__global__ __launch_bounds__(256) void qnn_kernel(
    const float* __restrict__ x,      // (B,4)
    const float* __restrict__ qw,     // (3,4)
    const float* __restrict__ W,      // (6,4)
    const float* __restrict__ bias,   // (6,)
    float* __restrict__ out,          // (B,6)
    int B)
{
    __shared__ float qw0[4], c1h[4], s1h[4], c2f[4], s2f[4], sW[24], sb[6];

    const int tid = threadIdx.x;
    if (tid < 4) {
        qw0[tid] = qw[tid];
        float r1 = qw[4 + tid] * (0.5f * INV_2PI);
        c1h[tid] = __builtin_amdgcn_cosf(r1);
        s1h[tid] = __builtin_amdgcn_sinf(r1);
        float r2 = qw[8 + tid] * INV_2PI;
        c2f[tid] = __builtin_amdgcn_cosf(r2);
        s2f[tid] = __builtin_amdgcn_sinf(r2);
    }
    if (tid < 24) sW[tid] = W[tid];
    if (tid < 6)  sb[tid] = bias[tid];
    __syncthreads();

    const size_t t  = (size_t)blockIdx.x * 256u + (size_t)tid;
    const size_t s0 = 2u * t;
    if (s0 < (size_t)B) {
        const float4* x4 = reinterpret_cast<const float4*>(x);
        if (s0 + 1 < (size_t)B) {
            // paired path: reads x4[s0], x4[s0+1]; writes out[12t .. 12t+11]
            float4 xa = x4[s0];
            float4 xb = x4[s0 + 1];
            float oa[6], ob[6];
            run_sample(xa.x, xa.y, xa.z, xa.w, qw0, c1h, s1h, c2f, s2f, sW, sb, oa);
            run_sample(xb.x, xb.y, xb.z, xb.w, qw0, c1h, s1h, c2f, s2f, sW, sb, ob);

            float* op = out + s0 * 6u;   // 16B-aligned: s0 even -> s0*6*4 % 16 == 0
            reinterpret_cast<float4*>(op)[0] = make_float4(oa[0], oa[1], oa[2], oa[3]);
            reinterpret_cast<float4*>(op)[1] = make_float4(oa[4], oa[5], ob[0], ob[1]);
            reinterpret_cast<float4*>(op)[2] = make_float4(ob[2], ob[3], ob[4], ob[5]);
        } else {
            // odd-B tail: one sample, scalar stores (always in-bounds)
            float4 xa = x4[s0];
            float oa[6];
            run_sample(xa.x, xa.y, xa.z, xa.w, qw0, c1h, s1h, c2f, s2f, sW, sb, oa);
            float* op = out + s0 * 6u;
#pragma unroll
            for (int j = 0; j < 6; ++j) op[j] = oa[j];
        }
    }
}

extern "C" void kernel_launch(void* const* d_in, const int* in_sizes, int n_in,
                              void* d_out, int out_size, void* d_ws, size_t ws_size,
                              hipStream_t stream) {
    const float* x    = (const float*)d_in[0];   // (B,4)
    const float* qw   = (const float*)d_in[1];   // (3,4)
    const float* W    = (const float*)d_in[2];   // (6,4)
    const float* bias = (const float*)d_in[3];   // (6,)
    float* out = (float*)d_out;

    const int B = in_sizes[0] / 4;
    const int threads = (B + 1) / 2;
    const int blocks = (threads + 255) / 256;
    qnn_kernel<<<blocks, 256, 0, stream>>>(x, qw, W, bias, out, B);
}